// Round 1
// baseline (1697.198 us; speedup 1.0000x reference)
//
#include <hip/hip_runtime.h>
#include <stdint.h>
#include <stddef.h>

// Problem constants (reference: NB=4, B=16, C=256, L=4096)
#define NBR 4
#define BSZ 16
#define CHN 256
#define LEN 4096
#define NB_B 64            // NBR*BSZ
#define BL   65536         // BSZ*LEN
#define BN_EPS 1e-5f

typedef unsigned short ushortT;
typedef unsigned short ushort8 __attribute__((ext_vector_type(8)));

__device__ __forceinline__ float bf2f(ushortT u) {
    return __uint_as_float(((unsigned)u) << 16);
}
__device__ __forceinline__ ushortT f2bf(float f) {
    unsigned b = __float_as_uint(f);
    return (ushortT)((b + 0x7FFFu + ((b >> 16) & 1u)) >> 16);
}
// order-preserving float->uint encoding (monotone); memset-0 init is below enc(-inf)
__device__ __forceinline__ unsigned encf(float f) {
    unsigned b = __float_as_uint(f);
    return (b & 0x80000000u) ? ~b : (b | 0x80000000u);
}
__device__ __forceinline__ float decf(unsigned u) {
    unsigned b = (u & 0x80000000u) ? (u ^ 0x80000000u) : ~u;
    return __uint_as_float(b);
}

// ---------------------------------------------------------------------------
// GEMM: Y[o,l] = sum_c W[o,c] * X[c,l]   per (n,b) slice.
// MODE 0: descriptor reduce (sum over l, max over l) -> atomics (no bias here)
// MODE 1: Y + bias -> bf16 store (v)
// MODE 2: X is bf16 (agg); Y + bias -> bf16 store (out_pre) + BN partial stats
// Tile: 128(o) x 128(l), K-chunk 16, 256 threads, 8x8 micro-tile per thread.
// ---------------------------------------------------------------------------
template <int MODE>
__global__ __launch_bounds__(256, 2)
void gemm_kernel(const void* __restrict__ act, const float* __restrict__ W,
                 const float* __restrict__ bias,
                 float* __restrict__ rsum, unsigned* __restrict__ rmax,
                 ushortT* __restrict__ store_out,
                 float* __restrict__ bnsum, float* __restrict__ bnss)
{
    __shared__ float sW[16 * 128];   // W^T chunk: sW[k][o]
    __shared__ float sX[16 * 128];   // X chunk:   sX[k][l]

    const int tid = threadIdx.x;
    const int ty = tid >> 4;         // 0..15 -> o sub-block
    const int tx = tid & 15;         // 0..15 -> l sub-block
    const int lt = blockIdx.x;       // 0..31
    const int ot = blockIdx.y;       // 0..1
    const int z  = blockIdx.z;       // n*16+b
    const int n  = z >> 4;
    const int obase = ot * 128;
    const int lbase = lt * 128;
    const float* Wn = W + (size_t)n * CHN * CHN;

    float acc[8][8];
#pragma unroll
    for (int r = 0; r < 8; ++r)
#pragma unroll
        for (int c = 0; c < 8; ++c) acc[r][c] = 0.f;

    for (int kb = 0; kb < CHN; kb += 16) {
        __syncthreads();
        // stage W^T chunk: 128 o x 16 k
#pragma unroll
        for (int q = 0; q < 2; ++q) {
            int f = tid * 2 + q;             // 0..511 float4 units
            int o = f >> 2;
            int c4 = (f & 3) << 2;
            const float4 w4 = *(const float4*)(Wn + (size_t)(obase + o) * CHN + kb + c4);
            sW[(c4 + 0) * 128 + o] = w4.x;
            sW[(c4 + 1) * 128 + o] = w4.y;
            sW[(c4 + 2) * 128 + o] = w4.z;
            sW[(c4 + 3) * 128 + o] = w4.w;
        }
        // stage X chunk: 16 k x 128 l (coalesced along l)
        {
            int k = ty;
            int l0 = tx * 8;
            size_t base = ((size_t)z * CHN + kb + k) * LEN + lbase + l0;
            if (MODE == 2) {
                ushort8 u = *(const ushort8*)((const ushortT*)act + base);
#pragma unroll
                for (int e = 0; e < 8; ++e) sX[k * 128 + l0 + e] = bf2f(u[e]);
            } else {
                const float* src = (const float*)act + base;
                float4 a = *(const float4*)src;
                float4 b4 = *(const float4*)(src + 4);
                *(float4*)&sX[k * 128 + l0] = a;
                *(float4*)&sX[k * 128 + l0 + 4] = b4;
            }
        }
        __syncthreads();
#pragma unroll
        for (int k = 0; k < 16; ++k) {
            float4 wa = *(const float4*)&sW[k * 128 + ty * 8];
            float4 wb = *(const float4*)&sW[k * 128 + ty * 8 + 4];
            float4 xa = *(const float4*)&sX[k * 128 + tx * 8];
            float4 xb = *(const float4*)&sX[k * 128 + tx * 8 + 4];
            float wv[8] = {wa.x, wa.y, wa.z, wa.w, wb.x, wb.y, wb.z, wb.w};
            float xv[8] = {xa.x, xa.y, xa.z, xa.w, xb.x, xb.y, xb.z, xb.w};
#pragma unroll
            for (int r = 0; r < 8; ++r)
#pragma unroll
                for (int c = 0; c < 8; ++c)
                    acc[r][c] = fmaf(wv[r], xv[c], acc[r][c]);
        }
    }

    if (MODE == 0) {
        // descriptor partials: per-o sum over this l-tile + max over this l-tile
        float rs[8], rm[8];
#pragma unroll
        for (int r = 0; r < 8; ++r) {
            float s = 0.f, m = -3.4e38f;
#pragma unroll
            for (int c = 0; c < 8; ++c) { s += acc[r][c]; m = fmaxf(m, acc[r][c]); }
            rs[r] = s; rm[r] = m;
        }
        __syncthreads();   // reuse sW/sX as reduction buffers [128][16]
#pragma unroll
        for (int r = 0; r < 8; ++r) {
            sW[(ty * 8 + r) * 16 + tx] = rs[r];
            sX[(ty * 8 + r) * 16 + tx] = rm[r];
        }
        __syncthreads();
        if (tid < 128) {
            float s = 0.f, m = -3.4e38f;
#pragma unroll
            for (int t = 0; t < 16; ++t) {
                s += sW[tid * 16 + t];
                m = fmaxf(m, sX[tid * 16 + t]);
            }
            int idx = z * CHN + obase + tid;
            atomicAdd(&rsum[idx], s);
            atomicMax(&rmax[idx], encf(m));
        }
    } else if (MODE == 1) {
#pragma unroll
        for (int r = 0; r < 8; ++r) {
            int o = obase + ty * 8 + r;
            float bv = bias[n * CHN + o];
            ushort8 u;
#pragma unroll
            for (int e = 0; e < 8; ++e) u[e] = f2bf(acc[r][e] + bv);
            *(ushort8*)(store_out + ((size_t)z * CHN + o) * LEN + lbase + tx * 8) = u;
        }
    } else {
        // MODE 2: out_pre store + BN partial stats (per (n=i, o) over b,l)
        float rs[8], rq[8];
#pragma unroll
        for (int r = 0; r < 8; ++r) {
            int o = obase + ty * 8 + r;
            float bo = bias[n * CHN + o];
            ushort8 u;
            float s = 0.f, q2 = 0.f;
#pragma unroll
            for (int e = 0; e < 8; ++e) {
                float v = acc[r][e] + bo;
                u[e] = f2bf(v);
                s += v; q2 += v * v;
            }
            *(ushort8*)(store_out + ((size_t)z * CHN + o) * LEN + lbase + tx * 8) = u;
            rs[r] = s; rq[r] = q2;
        }
        __syncthreads();
#pragma unroll
        for (int r = 0; r < 8; ++r) {
            sW[(ty * 8 + r) * 16 + tx] = rs[r];
            sX[(ty * 8 + r) * 16 + tx] = rq[r];
        }
        __syncthreads();
        if (tid < 128) {
            float s = 0.f, q2 = 0.f;
#pragma unroll
            for (int t = 0; t < 16; ++t) { s += sW[tid * 16 + t]; q2 += sX[tid * 16 + t]; }
            atomicAdd(&bnsum[n * CHN + obase + tid], s);
            atomicAdd(&bnss[n * CHN + obase + tid], q2);
        }
    }
}

// ---------------------------------------------------------------------------
// attention coefficients: scores[i,j,b] = (sum_c sq*sk) * edge_w[i,j] / 64
// attn[i,j,b] = softmax_j(scores) * softmax(branch_imp)[j]
// sq = qsum/L + dec(qmax) + 2*bq  (mean+max, bias shifts both by bq)
// ---------------------------------------------------------------------------
__global__ void attn_kernel(const float* __restrict__ qsum, const unsigned* __restrict__ qmax,
                            const float* __restrict__ ksum, const unsigned* __restrict__ kmax,
                            const float* __restrict__ bq, const float* __restrict__ bk,
                            const float* __restrict__ edge, const float* __restrict__ bimp,
                            float* __restrict__ attn)
{
    __shared__ float sc[NBR][NBR][BSZ];
    int tid = threadIdx.x;           // 256 threads == 4*4*16
    int i = tid >> 6, j = (tid >> 4) & 3, b = tid & 15;
    float s = 0.f;
    const float invL = 1.0f / (float)LEN;
    for (int c = 0; c < CHN; ++c) {
        int qi = (i * BSZ + b) * CHN + c;
        int ki = (j * BSZ + b) * CHN + c;
        float sq = qsum[qi] * invL + decf(qmax[qi]) + 2.f * bq[i * CHN + c];
        float sk = ksum[ki] * invL + decf(kmax[ki]) + 2.f * bk[j * CHN + c];
        s += sq * sk;
    }
    sc[i][j][b] = s * edge[i * 4 + j] * (1.0f / 64.0f);
    __syncthreads();
    if (tid < 64) {
        int ii = tid >> 4, bb = tid & 15;
        float m = -3.4e38f;
        for (int jj = 0; jj < 4; ++jj) m = fmaxf(m, sc[ii][jj][bb]);
        float e[4]; float sum = 0.f;
        for (int jj = 0; jj < 4; ++jj) { e[jj] = __expf(sc[ii][jj][bb] - m); sum += e[jj]; }
        // branch-importance softmax (redundant per thread, 4 elements)
        float bm = fmaxf(fmaxf(bimp[0], bimp[1]), fmaxf(bimp[2], bimp[3]));
        float be[4]; float bs = 0.f;
        for (int jj = 0; jj < 4; ++jj) { be[jj] = __expf(bimp[jj] - bm); bs += be[jj]; }
        for (int jj = 0; jj < 4; ++jj)
            attn[(ii * 4 + jj) * BSZ + bb] = (e[jj] / sum) * (be[jj] / bs);
    }
}

// agg[i,b,c,l] = sum_j attn[i,j,b] * v[j,b,c,l]   (bf16 in, bf16 out)
__global__ __launch_bounds__(256)
void agg_kernel(const ushortT* __restrict__ v, const float* __restrict__ attn,
                ushortT* __restrict__ agg)
{
    __shared__ float sa[256];
    sa[threadIdx.x] = attn[threadIdx.x];
    __syncthreads();
    const long long U = (long long)BSZ * CHN * (LEN / 8);   // 2,097,152 units of 8
    for (long long u = (long long)blockIdx.x * blockDim.x + threadIdx.x; u < U;
         u += (long long)gridDim.x * blockDim.x) {
        int l0 = (int)(u & 511) * 8;
        int c  = (int)(u >> 9) & 255;
        int b  = (int)(u >> 17);
        float vv[4][8];
#pragma unroll
        for (int j = 0; j < 4; ++j) {
            ushort8 raw = *(const ushort8*)(v + (((size_t)(j * BSZ + b) * CHN + c) * LEN) + l0);
#pragma unroll
            for (int e = 0; e < 8; ++e) vv[j][e] = bf2f(raw[e]);
        }
#pragma unroll
        for (int i = 0; i < 4; ++i) {
            float a0 = sa[(i * 4 + 0) * BSZ + b];
            float a1 = sa[(i * 4 + 1) * BSZ + b];
            float a2 = sa[(i * 4 + 2) * BSZ + b];
            float a3 = sa[(i * 4 + 3) * BSZ + b];
            ushort8 out;
#pragma unroll
            for (int e = 0; e < 8; ++e) {
                float r = a0 * vv[0][e] + a1 * vv[1][e] + a2 * vv[2][e] + a3 * vv[3][e];
                out[e] = f2bf(r);
            }
            *(ushort8*)(agg + (((size_t)(i * BSZ + b) * CHN + c) * LEN) + l0) = out;
        }
    }
}

// finalize BN affine: scale = gamma*rsqrt(var+eps), shift = beta - mean*scale
__global__ void bnfin_kernel(const float* __restrict__ bnsum, const float* __restrict__ bnss,
                             const float* __restrict__ gamma, const float* __restrict__ beta,
                             float* __restrict__ scl, float* __restrict__ shf)
{
    int t = blockIdx.x * blockDim.x + threadIdx.x;   // 0..1023 = n*256+c
    if (t < NBR * CHN) {
        const float inv = 1.0f / (float)BL;
        float mean = bnsum[t] * inv;
        float var = bnss[t] * inv - mean * mean;
        float rs = rsqrtf(var + BN_EPS);
        float s = gamma[t] * rs;
        scl[t] = s;
        shf[t] = beta[t] - mean * s;
    }
}

// out = relu(out_pre*scale + shift) + x
__global__ __launch_bounds__(256)
void final_kernel(const ushortT* __restrict__ outpre, const float* __restrict__ x,
                  const float* __restrict__ scl, const float* __restrict__ shf,
                  float* __restrict__ out)
{
    const long long U = (long long)NB_B * CHN * (LEN / 8);   // 8,388,608 units of 8
    for (long long u = (long long)blockIdx.x * blockDim.x + threadIdx.x; u < U;
         u += (long long)gridDim.x * blockDim.x) {
        int l0 = (int)(u & 511) * 8;
        int c  = (int)(u >> 9) & 255;
        int zz = (int)(u >> 17);          // n*16+b
        int n  = zz >> 4;
        size_t base = ((size_t)zz * CHN + c) * LEN + l0;
        ushort8 op = *(const ushort8*)(outpre + base);
        float4 x0 = *(const float4*)(x + base);
        float4 x1 = *(const float4*)(x + base + 4);
        float sc = scl[n * CHN + c];
        float sh = shf[n * CHN + c];
        float xr[8] = {x0.x, x0.y, x0.z, x0.w, x1.x, x1.y, x1.z, x1.w};
        float res[8];
#pragma unroll
        for (int e = 0; e < 8; ++e) {
            float bn = bf2f(op[e]) * sc + sh;
            res[e] = fmaxf(bn, 0.f) + xr[e];
        }
        float4 o0 = {res[0], res[1], res[2], res[3]};
        float4 o1 = {res[4], res[5], res[6], res[7]};
        *(float4*)(out + base) = o0;
        *(float4*)(out + base + 4) = o1;
    }
}

extern "C" void kernel_launch(void* const* d_in, const int* in_sizes, int n_in,
                              void* d_out, int out_size, void* d_ws, size_t ws_size,
                              hipStream_t stream)
{
    const float* x     = (const float*)d_in[0];
    const float* Wq    = (const float*)d_in[1];
    const float* bq    = (const float*)d_in[2];
    const float* Wk    = (const float*)d_in[3];
    const float* bk    = (const float*)d_in[4];
    const float* Wv    = (const float*)d_in[5];
    const float* bv    = (const float*)d_in[6];
    const float* Wo    = (const float*)d_in[7];
    const float* bo    = (const float*)d_in[8];
    const float* gamma = (const float*)d_in[9];
    const float* beta  = (const float*)d_in[10];
    const float* edge  = (const float*)d_in[11];
    const float* bimp  = (const float*)d_in[12];

    char* ws = (char*)d_ws;
    const size_t V_BYTES = (size_t)NBR * BSZ * CHN * LEN * 2;   // 128 MiB (bf16)
    ushortT* vbuf = (ushortT*)ws;            // v, later reused for out_pre
    size_t off = V_BYTES;
    float*    qsum = (float*)(ws + off);    off += 65536;
    unsigned* qmax = (unsigned*)(ws + off); off += 65536;
    float*    ksum = (float*)(ws + off);    off += 65536;
    unsigned* kmax = (unsigned*)(ws + off); off += 65536;
    float*    attn = (float*)(ws + off);    off += 1024;
    float*    bnsum= (float*)(ws + off);    off += 4096;
    float*    bnss = (float*)(ws + off);    off += 4096;
    float*    scl  = (float*)(ws + off);    off += 4096;
    float*    shf  = (float*)(ws + off);    off += 4096;

    // zero the small accumulators (sum=0; max uses encoding where 0 < enc(-inf))
    hipMemsetAsync(ws + V_BYTES, 0, off - V_BYTES, stream);

    ushortT* aggbuf = (ushortT*)d_out;   // agg staged as bf16 in d_out (first 128 MiB)
    float*   outf   = (float*)d_out;

    dim3 gg(LEN / 128, CHN / 128, NB_B);   // (32, 2, 64)

    gemm_kernel<0><<<gg, 256, 0, stream>>>(x, Wq, nullptr, qsum, qmax, nullptr, nullptr, nullptr);
    gemm_kernel<0><<<gg, 256, 0, stream>>>(x, Wk, nullptr, ksum, kmax, nullptr, nullptr, nullptr);
    gemm_kernel<1><<<gg, 256, 0, stream>>>(x, Wv, bv, nullptr, nullptr, vbuf, nullptr, nullptr);
    attn_kernel<<<1, 256, 0, stream>>>(qsum, qmax, ksum, kmax, bq, bk, edge, bimp, attn);
    agg_kernel<<<2048, 256, 0, stream>>>(vbuf, attn, aggbuf);
    gemm_kernel<2><<<gg, 256, 0, stream>>>(aggbuf, Wo, bo, nullptr, nullptr, vbuf, bnsum, bnss);
    bnfin_kernel<<<4, 256, 0, stream>>>(bnsum, bnss, gamma, beta, scl, shf);
    final_kernel<<<8192, 256, 0, stream>>>(vbuf, x, scl, shf, outf);
}

// Round 3
// 560.685 us; speedup vs baseline: 3.0270x; 3.0270x over previous
//
#include <hip/hip_runtime.h>
#include <stdint.h>
#include <stddef.h>

// Problem constants (reference: NB=4, B=16, C=256, L=4096)
#define NBR 4
#define BSZ 16
#define CHN 256
#define LEN 4096
#define NB_B 64            // NBR*BSZ
#define BL   65536         // BSZ*LEN
#define BN_EPS 1e-5f
#define W_EL (NBR*CHN*CHN) // 262144 elements per weight tensor

typedef unsigned short ushortT;
typedef unsigned short ushort4_t __attribute__((ext_vector_type(4)));
typedef unsigned short ushort8_t __attribute__((ext_vector_type(8)));
typedef short bf16x8 __attribute__((ext_vector_type(8)));
typedef float f32x4 __attribute__((ext_vector_type(4)));

__device__ __forceinline__ float bf2f(ushortT u) {
    return __uint_as_float(((unsigned)u) << 16);
}
__device__ __forceinline__ ushortT f2bf(float f) {
    unsigned b = __float_as_uint(f);
    return (ushortT)((b + 0x7FFFu + ((b >> 16) & 1u)) >> 16);
}
// order-preserving float->uint encoding (monotone); memset-0 init is below enc(-inf)
__device__ __forceinline__ unsigned encf(float f) {
    unsigned b = __float_as_uint(f);
    return (b & 0x80000000u) ? ~b : (b | 0x80000000u);
}
__device__ __forceinline__ float decf(unsigned u) {
    unsigned b = (u & 0x80000000u) ? (u ^ 0x80000000u) : ~u;
    return __uint_as_float(b);
}

// LDS swizzles (byte offsets). sX rows are 512B (256 c bf16), sW rows 128B (64 c bf16).
__device__ __forceinline__ int swzX(int row, int cb) {
    return row * 512 + (cb ^ ((row & 7) << 4) ^ (((row >> 3) & 3) << 7));
}
__device__ __forceinline__ int swzW(int row, int cb) {
    return row * 128 + (cb ^ ((row & 7) << 4));
}

// Stage x-tile [l=128][c=256] into LDS, transposed+converted, swizzled.
// BF16IN=false: fp32 source (x); true: bf16 source (agg).
template <bool BF16IN>
__device__ __forceinline__ void stage_x(const void* act, ushortT* sX, int z, int lbase, int tid)
{
    const int ls = tid & 127;
    const int gh = tid >> 7;
    if (BF16IN) {
        const ushortT* xp = (const ushortT*)act + (size_t)z * CHN * LEN + lbase + ls;
#pragma unroll
        for (int g = 0; g < 16; ++g) {
            int c0 = (gh * 16 + g) * 8;
            ushort8_t u;
#pragma unroll
            for (int i = 0; i < 8; ++i) u[i] = xp[(size_t)(c0 + i) * LEN];
            *(ushort8_t*)((char*)sX + swzX(ls, c0 * 2)) = u;
        }
    } else {
        const float* xp = (const float*)act + (size_t)z * CHN * LEN + lbase + ls;
#pragma unroll
        for (int g = 0; g < 16; ++g) {
            int c0 = (gh * 16 + g) * 8;
            ushort8_t u;
#pragma unroll
            for (int i = 0; i < 8; ++i) u[i] = f2bf(xp[(size_t)(c0 + i) * LEN]);
            *(ushort8_t*)((char*)sX + swzX(ls, c0 * 2)) = u;
        }
    }
}

// Stage W chunk [o=128][c=64] (bf16 source) into LDS, swizzled.
__device__ __forceinline__ void stage_w(const ushortT* Wb, ushortT* sW, int obase, int kb, int tid)
{
    const int r = tid >> 1;
    const int h = tid & 1;
    const ushortT* wp = Wb + (size_t)(obase + r) * CHN + kb + h * 32;
#pragma unroll
    for (int i = 0; i < 4; ++i) {
        ushort8_t u = *(const ushort8_t*)(wp + i * 8);
        *(ushort8_t*)((char*)sW + swzW(r, h * 64 + i * 16)) = u;
    }
}

// One K-chunk (64) of MFMA: A = x-frags (M=l), B = W-frags (N=o).
__device__ __forceinline__ void mfma_chunk(const ushortT* sX, const ushortT* sW,
                                           f32x4 acc[4][4], int wr, int wc, int lane, int kb)
{
    const int am = wr * 64 + (lane & 15);
    const int bo = wc * 64 + (lane & 15);
    const int kg = (lane >> 4) * 16;   // byte offset of this lane's k-group
#pragma unroll
    for (int s = 0; s < 2; ++s) {
        bf16x8 a[4], b[4];
#pragma unroll
        for (int mf = 0; mf < 4; ++mf)
            a[mf] = *(const bf16x8*)((const char*)sX + swzX(am + mf * 16, kb * 2 + s * 64 + kg));
#pragma unroll
        for (int nf = 0; nf < 4; ++nf)
            b[nf] = *(const bf16x8*)((const char*)sW + swzW(bo + nf * 16, s * 64 + kg));
#pragma unroll
        for (int mf = 0; mf < 4; ++mf)
#pragma unroll
            for (int nf = 0; nf < 4; ++nf)
                acc[mf][nf] = __builtin_amdgcn_mfma_f32_16x16x32_bf16(a[mf], b[nf], acc[mf][nf], 0, 0, 0);
    }
}

// ---------------------------------------------------------------------------
// QKV fused: stage x-tile once, run 6 GEMM-tiles (Wq,Wk,Wv x 2 o-halves).
// Wq/Wk epilogue: per-o sum & max over l -> atomics. Wv: bias + bf16 store.
// ---------------------------------------------------------------------------
__global__ __launch_bounds__(256, 2)
void qkv_kernel(const float* __restrict__ x, const ushortT* __restrict__ Wbf,
                const float* __restrict__ bv,
                float* __restrict__ qsum, unsigned* __restrict__ qmax,
                float* __restrict__ ksum, unsigned* __restrict__ kmax,
                ushortT* __restrict__ vbuf)
{
    __shared__ ushortT sX[128 * 256];   // 64 KiB
    __shared__ ushortT sW[128 * 64];    // 16 KiB
    const int tid = threadIdx.x;
    const int lane = tid & 63;
    const int wv = tid >> 6;
    const int wr = wv >> 1, wc = wv & 1;
    const int lbase = blockIdx.x * 128;
    const int z = blockIdx.y;
    const int n = z >> 4;

    stage_x<false>(x, sX, z, lbase, tid);

    for (int w = 0; w < 3; ++w) {
        const ushortT* Wb = Wbf + ((size_t)w * NBR + n) * CHN * CHN;
        for (int ot = 0; ot < 2; ++ot) {
            const int obase = ot * 128;
            f32x4 acc[4][4];
            const f32x4 z4 = {0.f, 0.f, 0.f, 0.f};
#pragma unroll
            for (int mf = 0; mf < 4; ++mf)
#pragma unroll
                for (int nf = 0; nf < 4; ++nf) acc[mf][nf] = z4;

            for (int kb = 0; kb < 4; ++kb) {
                __syncthreads();
                stage_w(Wb, sW, obase, kb * 64, tid);
                __syncthreads();
                mfma_chunk(sX, sW, acc, wr, wc, lane, kb * 64);
            }

            if (w < 2) {
                float* rs = (w == 0) ? qsum : ksum;
                unsigned* rm = (w == 0) ? qmax : kmax;
#pragma unroll
                for (int nf = 0; nf < 4; ++nf) {
                    float s = 0.f, m = -3.4e38f;
#pragma unroll
                    for (int mf = 0; mf < 4; ++mf)
#pragma unroll
                        for (int r = 0; r < 4; ++r) {
                            float v = acc[mf][nf][r];
                            s += v; m = fmaxf(m, v);
                        }
                    s += __shfl_xor(s, 16); s += __shfl_xor(s, 32);
                    m = fmaxf(m, __shfl_xor(m, 16)); m = fmaxf(m, __shfl_xor(m, 32));
                    if (lane < 16) {
                        int o = obase + wc * 64 + nf * 16 + lane;
                        atomicAdd(&rs[z * CHN + o], s);
                        atomicMax(&rm[z * CHN + o], encf(m));
                    }
                }
            } else {
#pragma unroll
                for (int nf = 0; nf < 4; ++nf) {
                    int o = obase + wc * 64 + nf * 16 + (lane & 15);
                    float bvv = bv[n * CHN + o];
#pragma unroll
                    for (int mf = 0; mf < 4; ++mf) {
                        int l = lbase + wr * 64 + mf * 16 + ((lane >> 4) << 2);
                        ushort4_t u;
#pragma unroll
                        for (int r = 0; r < 4; ++r) u[r] = f2bf(acc[mf][nf][r] + bvv);
                        *(ushort4_t*)(vbuf + (size_t)(z * CHN + o) * LEN + l) = u;
                    }
                }
            }
        }
    }
}

// ---------------------------------------------------------------------------
// O GEMM: agg (bf16) -> out_pre (bf16) + BN partial stats.
// ---------------------------------------------------------------------------
__global__ __launch_bounds__(256, 2)
void ogemm_kernel(const ushortT* __restrict__ agg, const ushortT* __restrict__ Wbo,
                  const float* __restrict__ bo_,
                  float* __restrict__ bnsum, float* __restrict__ bnss,
                  ushortT* __restrict__ outpre)
{
    __shared__ ushortT sX[128 * 256];
    __shared__ ushortT sW[128 * 64];
    const int tid = threadIdx.x;
    const int lane = tid & 63;
    const int wv = tid >> 6;
    const int wr = wv >> 1, wc = wv & 1;
    const int lbase = blockIdx.x * 128;
    const int z = blockIdx.y;
    const int n = z >> 4;
    // FIX (round 2): per-branch weight slice — round 1 used branch 0's Wo for all n.
    const ushortT* Wb = Wbo + (size_t)n * CHN * CHN;

    stage_x<true>(agg, sX, z, lbase, tid);

    for (int ot = 0; ot < 2; ++ot) {
        const int obase = ot * 128;
        f32x4 acc[4][4];
        const f32x4 z4 = {0.f, 0.f, 0.f, 0.f};
#pragma unroll
        for (int mf = 0; mf < 4; ++mf)
#pragma unroll
            for (int nf = 0; nf < 4; ++nf) acc[mf][nf] = z4;

        for (int kb = 0; kb < 4; ++kb) {
            __syncthreads();
            stage_w(Wb, sW, obase, kb * 64, tid);
            __syncthreads();
            mfma_chunk(sX, sW, acc, wr, wc, lane, kb * 64);
        }

#pragma unroll
        for (int nf = 0; nf < 4; ++nf) {
            int o = obase + wc * 64 + nf * 16 + (lane & 15);
            float bb = bo_[n * CHN + o];
            float s = 0.f, q2 = 0.f;
#pragma unroll
            for (int mf = 0; mf < 4; ++mf) {
                int l = lbase + wr * 64 + mf * 16 + ((lane >> 4) << 2);
                ushort4_t u;
#pragma unroll
                for (int r = 0; r < 4; ++r) {
                    float v = acc[mf][nf][r] + bb;
                    u[r] = f2bf(v);
                    s += v; q2 += v * v;
                }
                *(ushort4_t*)(outpre + (size_t)(z * CHN + o) * LEN + l) = u;
            }
            s += __shfl_xor(s, 16); s += __shfl_xor(s, 32);
            q2 += __shfl_xor(q2, 16); q2 += __shfl_xor(q2, 32);
            if (lane < 16) {
                atomicAdd(&bnsum[n * CHN + o], s);
                atomicAdd(&bnss[n * CHN + o], q2);
            }
        }
    }
}

// convert all 4 weight tensors fp32 -> bf16 into Wbf [w][n][o][c]
__global__ void wcvt_kernel(const float* __restrict__ Wq, const float* __restrict__ Wk,
                            const float* __restrict__ Wv, const float* __restrict__ Wo,
                            ushortT* __restrict__ Wbf)
{
    int t = blockIdx.x * 256 + threadIdx.x;    // float4 units
    const int per = W_EL / 4;                  // 65536
    if (t < 4 * per) {
        const float* srcs[4] = {Wq, Wk, Wv, Wo};
        int w = t / per;
        int r = t - w * per;
        float4 f = *(const float4*)(srcs[w] + (size_t)r * 4);
        ushort4_t u = {f2bf(f.x), f2bf(f.y), f2bf(f.z), f2bf(f.w)};
        *(ushort4_t*)(Wbf + (size_t)w * W_EL + (size_t)r * 4) = u;
    }
}

// ---------------------------------------------------------------------------
// attention coefficients: scores[i,j,b] = (sum_c sq*sk) * edge_w[i,j] / 64
// attn[i,j,b] = softmax_j(scores) * softmax(branch_imp)[j]
// sq = qsum/L + dec(qmax) + 2*bq  (mean+max, bias shifts both by bq)
// ---------------------------------------------------------------------------
__global__ void attn_kernel(const float* __restrict__ qsum, const unsigned* __restrict__ qmax,
                            const float* __restrict__ ksum, const unsigned* __restrict__ kmax,
                            const float* __restrict__ bq, const float* __restrict__ bk,
                            const float* __restrict__ edge, const float* __restrict__ bimp,
                            float* __restrict__ attn)
{
    __shared__ float sc[NBR][NBR][BSZ];
    int tid = threadIdx.x;           // 256 threads == 4*4*16
    int i = tid >> 6, j = (tid >> 4) & 3, b = tid & 15;
    float s = 0.f;
    const float invL = 1.0f / (float)LEN;
    for (int c = 0; c < CHN; ++c) {
        int qi = (i * BSZ + b) * CHN + c;
        int ki = (j * BSZ + b) * CHN + c;
        float sq = qsum[qi] * invL + decf(qmax[qi]) + 2.f * bq[i * CHN + c];
        float sk = ksum[ki] * invL + decf(kmax[ki]) + 2.f * bk[j * CHN + c];
        s += sq * sk;
    }
    sc[i][j][b] = s * edge[i * 4 + j] * (1.0f / 64.0f);
    __syncthreads();
    if (tid < 64) {
        int ii = tid >> 4, bb = tid & 15;
        float m = -3.4e38f;
        for (int jj = 0; jj < 4; ++jj) m = fmaxf(m, sc[ii][jj][bb]);
        float e[4]; float sum = 0.f;
        for (int jj = 0; jj < 4; ++jj) { e[jj] = __expf(sc[ii][jj][bb] - m); sum += e[jj]; }
        float bm = fmaxf(fmaxf(bimp[0], bimp[1]), fmaxf(bimp[2], bimp[3]));
        float be[4]; float bs = 0.f;
        for (int jj = 0; jj < 4; ++jj) { be[jj] = __expf(bimp[jj] - bm); bs += be[jj]; }
        for (int jj = 0; jj < 4; ++jj)
            attn[(ii * 4 + jj) * BSZ + bb] = (e[jj] / sum) * (be[jj] / bs);
    }
}

// agg[i,b,c,l] = sum_j attn[i,j,b] * v[j,b,c,l]   (bf16 in, bf16 out)
__global__ __launch_bounds__(256)
void agg_kernel(const ushortT* __restrict__ v, const float* __restrict__ attn,
                ushortT* __restrict__ agg)
{
    __shared__ float sa[256];
    sa[threadIdx.x] = attn[threadIdx.x];
    __syncthreads();
    const long long U = (long long)BSZ * CHN * (LEN / 8);   // 2,097,152 units of 8
    for (long long u = (long long)blockIdx.x * blockDim.x + threadIdx.x; u < U;
         u += (long long)gridDim.x * blockDim.x) {
        int l0 = (int)(u & 511) * 8;
        int c  = (int)(u >> 9) & 255;
        int b  = (int)(u >> 17);
        float vv[4][8];
#pragma unroll
        for (int j = 0; j < 4; ++j) {
            ushort8_t raw = *(const ushort8_t*)(v + (((size_t)(j * BSZ + b) * CHN + c) * LEN) + l0);
#pragma unroll
            for (int e = 0; e < 8; ++e) vv[j][e] = bf2f(raw[e]);
        }
#pragma unroll
        for (int i = 0; i < 4; ++i) {
            float a0 = sa[(i * 4 + 0) * BSZ + b];
            float a1 = sa[(i * 4 + 1) * BSZ + b];
            float a2 = sa[(i * 4 + 2) * BSZ + b];
            float a3 = sa[(i * 4 + 3) * BSZ + b];
            ushort8_t out;
#pragma unroll
            for (int e = 0; e < 8; ++e) {
                float r = a0 * vv[0][e] + a1 * vv[1][e] + a2 * vv[2][e] + a3 * vv[3][e];
                out[e] = f2bf(r);
            }
            *(ushort8_t*)(agg + (((size_t)(i * BSZ + b) * CHN + c) * LEN) + l0) = out;
        }
    }
}

// finalize BN affine: scale = gamma*rsqrt(var+eps), shift = beta - mean*scale
__global__ void bnfin_kernel(const float* __restrict__ bnsum, const float* __restrict__ bnss,
                             const float* __restrict__ gamma, const float* __restrict__ beta,
                             float* __restrict__ scl, float* __restrict__ shf)
{
    int t = blockIdx.x * blockDim.x + threadIdx.x;   // 0..1023 = n*256+c
    if (t < NBR * CHN) {
        const float inv = 1.0f / (float)BL;
        float mean = bnsum[t] * inv;
        float var = bnss[t] * inv - mean * mean;
        float rs = rsqrtf(var + BN_EPS);
        float s = gamma[t] * rs;
        scl[t] = s;
        shf[t] = beta[t] - mean * s;
    }
}

// out = relu(out_pre*scale + shift) + x
__global__ __launch_bounds__(256)
void final_kernel(const ushortT* __restrict__ outpre, const float* __restrict__ x,
                  const float* __restrict__ scl, const float* __restrict__ shf,
                  float* __restrict__ out)
{
    const long long U = (long long)NB_B * CHN * (LEN / 8);   // 8,388,608 units of 8
    for (long long u = (long long)blockIdx.x * blockDim.x + threadIdx.x; u < U;
         u += (long long)gridDim.x * blockDim.x) {
        int l0 = (int)(u & 511) * 8;
        int c  = (int)(u >> 9) & 255;
        int zz = (int)(u >> 17);          // n*16+b
        int n  = zz >> 4;
        size_t base = ((size_t)zz * CHN + c) * LEN + l0;
        ushort8_t op = *(const ushort8_t*)(outpre + base);
        float4 x0 = *(const float4*)(x + base);
        float4 x1 = *(const float4*)(x + base + 4);
        float sc = scl[n * CHN + c];
        float sh = shf[n * CHN + c];
        float xr[8] = {x0.x, x0.y, x0.z, x0.w, x1.x, x1.y, x1.z, x1.w};
        float res[8];
#pragma unroll
        for (int e = 0; e < 8; ++e) {
            float bn = bf2f(op[e]) * sc + sh;
            res[e] = fmaxf(bn, 0.f) + xr[e];
        }
        float4 o0 = {res[0], res[1], res[2], res[3]};
        float4 o1 = {res[4], res[5], res[6], res[7]};
        *(float4*)(out + base) = o0;
        *(float4*)(out + base + 4) = o1;
    }
}

extern "C" void kernel_launch(void* const* d_in, const int* in_sizes, int n_in,
                              void* d_out, int out_size, void* d_ws, size_t ws_size,
                              hipStream_t stream)
{
    const float* x     = (const float*)d_in[0];
    const float* Wq    = (const float*)d_in[1];
    const float* bq    = (const float*)d_in[2];
    const float* Wk    = (const float*)d_in[3];
    const float* bk    = (const float*)d_in[4];
    const float* Wv    = (const float*)d_in[5];
    const float* bv    = (const float*)d_in[6];
    const float* Wo    = (const float*)d_in[7];
    const float* bo    = (const float*)d_in[8];
    const float* gamma = (const float*)d_in[9];
    const float* beta  = (const float*)d_in[10];
    const float* edge  = (const float*)d_in[11];
    const float* bimp  = (const float*)d_in[12];

    char* ws = (char*)d_ws;
    const size_t V_BYTES = (size_t)NBR * BSZ * CHN * LEN * 2;   // 128 MiB (bf16)
    ushortT* vbuf = (ushortT*)ws;            // v, later reused for out_pre
    size_t off = V_BYTES;
    float*    qsum = (float*)(ws + off);    off += 65536;
    unsigned* qmax = (unsigned*)(ws + off); off += 65536;
    float*    ksum = (float*)(ws + off);    off += 65536;
    unsigned* kmax = (unsigned*)(ws + off); off += 65536;
    float*    attn = (float*)(ws + off);    off += 1024;
    float*    bnsum= (float*)(ws + off);    off += 4096;
    float*    bnss = (float*)(ws + off);    off += 4096;
    float*    scl  = (float*)(ws + off);    off += 4096;
    float*    shf  = (float*)(ws + off);    off += 4096;

    // zero the small accumulators (sum=0; max uses encoding where 0 < enc(-inf))
    hipMemsetAsync(ws + V_BYTES, 0, off - V_BYTES, stream);

    ushortT* aggbuf = (ushortT*)d_out;   // agg staged as bf16 in d_out (first 128 MiB)
    float*   outf   = (float*)d_out;
    // bf16 weights live in the (unused until final) second half of d_out
    ushortT* Wbf = (ushortT*)((char*)d_out + ((size_t)134217728));

    wcvt_kernel<<<(4 * W_EL / 4 + 255) / 256, 256, 0, stream>>>(Wq, Wk, Wv, Wo, Wbf);

    dim3 gq(LEN / 128, NB_B);   // (32, 64)
    qkv_kernel<<<gq, 256, 0, stream>>>(x, Wbf, bv, qsum, qmax, ksum, kmax, vbuf);
    attn_kernel<<<1, 256, 0, stream>>>(qsum, qmax, ksum, kmax, bq, bk, edge, bimp, attn);
    agg_kernel<<<2048, 256, 0, stream>>>(vbuf, attn, aggbuf);
    ogemm_kernel<<<gq, 256, 0, stream>>>(aggbuf, Wbf + (size_t)3 * W_EL, bo, bnsum, bnss, vbuf);
    bnfin_kernel<<<4, 256, 0, stream>>>(bnsum, bnss, gamma, beta, scl, shf);
    final_kernel<<<8192, 256, 0, stream>>>(vbuf, x, scl, shf, outf);
}

// Round 4
// 524.916 us; speedup vs baseline: 3.2333x; 1.0681x over previous
//
#include <hip/hip_runtime.h>
#include <stdint.h>
#include <stddef.h>

// Problem constants (reference: NB=4, B=16, C=256, L=4096)
#define NBR 4
#define BSZ 16
#define CHN 256
#define LEN 4096
#define NB_B 64            // NBR*BSZ
#define BL   65536         // BSZ*LEN
#define BN_EPS 1e-5f
#define W_EL (NBR*CHN*CHN) // 262144 elements per weight tensor

typedef unsigned short ushortT;
typedef unsigned short ushort4_t __attribute__((ext_vector_type(4)));
typedef unsigned short ushort8_t __attribute__((ext_vector_type(8)));
typedef short bf16x8 __attribute__((ext_vector_type(8)));
typedef float f32x4 __attribute__((ext_vector_type(4)));

__device__ __forceinline__ float bf2f(ushortT u) {
    return __uint_as_float(((unsigned)u) << 16);
}
__device__ __forceinline__ ushortT f2bf(float f) {
    unsigned b = __float_as_uint(f);
    return (ushortT)((b + 0x7FFFu + ((b >> 16) & 1u)) >> 16);
}
// order-preserving float->uint encoding (monotone); memset-0 init is below enc(-inf)
__device__ __forceinline__ unsigned encf(float f) {
    unsigned b = __float_as_uint(f);
    return (b & 0x80000000u) ? ~b : (b | 0x80000000u);
}
__device__ __forceinline__ float decf(unsigned u) {
    unsigned b = (u & 0x80000000u) ? (u ^ 0x80000000u) : ~u;
    return __uint_as_float(b);
}

// LDS swizzles (byte offsets). sX rows are 512B (256 c bf16), sW rows 128B (64 c bf16).
__device__ __forceinline__ int swzX(int row, int cb) {
    return row * 512 + (cb ^ ((row & 7) << 4) ^ (((row >> 3) & 3) << 7));
}
__device__ __forceinline__ int swzW(int row, int cb) {
    return row * 128 + (cb ^ ((row & 7) << 4));
}

// Stage x-tile [l=128][c=256] into LDS, transposed+converted, swizzled.
// BF16IN=false: fp32 source (x); true: bf16 source (agg).
template <bool BF16IN>
__device__ __forceinline__ void stage_x(const void* act, ushortT* sX, int z, int lbase, int tid)
{
    const int ls = tid & 127;
    const int gh = tid >> 7;
    if (BF16IN) {
        const ushortT* xp = (const ushortT*)act + (size_t)z * CHN * LEN + lbase + ls;
#pragma unroll
        for (int g = 0; g < 16; ++g) {
            int c0 = (gh * 16 + g) * 8;
            ushort8_t u;
#pragma unroll
            for (int i = 0; i < 8; ++i) u[i] = xp[(size_t)(c0 + i) * LEN];
            *(ushort8_t*)((char*)sX + swzX(ls, c0 * 2)) = u;
        }
    } else {
        const float* xp = (const float*)act + (size_t)z * CHN * LEN + lbase + ls;
#pragma unroll
        for (int g = 0; g < 16; ++g) {
            int c0 = (gh * 16 + g) * 8;
            ushort8_t u;
#pragma unroll
            for (int i = 0; i < 8; ++i) u[i] = f2bf(xp[(size_t)(c0 + i) * LEN]);
            *(ushort8_t*)((char*)sX + swzX(ls, c0 * 2)) = u;
        }
    }
}

// T14 async-STAGE split for W chunk [o=128][c=64] (bf16 source):
// issue-early global->reg, write-late reg->LDS (swizzled).
__device__ __forceinline__ void stage_w_load(const ushortT* Wb, int obase, int kb, int tid,
                                             ushort8_t wreg[4])
{
    const int r = tid >> 1;
    const int h = tid & 1;
    const ushortT* wp = Wb + (size_t)(obase + r) * CHN + kb + h * 32;
#pragma unroll
    for (int i = 0; i < 4; ++i) wreg[i] = *(const ushort8_t*)(wp + i * 8);
}
__device__ __forceinline__ void stage_w_write(ushortT* sW, int tid, const ushort8_t wreg[4])
{
    const int r = tid >> 1;
    const int h = tid & 1;
#pragma unroll
    for (int i = 0; i < 4; ++i)
        *(ushort8_t*)((char*)sW + swzW(r, h * 64 + i * 16)) = wreg[i];
}

// One K-chunk (64) of MFMA: A = x-frags (M=l), B = W-frags (N=o).
__device__ __forceinline__ void mfma_chunk(const ushortT* sX, const ushortT* sW,
                                           f32x4 acc[4][4], int wr, int wc, int lane, int kb)
{
    const int am = wr * 64 + (lane & 15);
    const int bo = wc * 64 + (lane & 15);
    const int kg = (lane >> 4) * 16;   // byte offset of this lane's k-group
#pragma unroll
    for (int s = 0; s < 2; ++s) {
        bf16x8 a[4], b[4];
#pragma unroll
        for (int mf = 0; mf < 4; ++mf)
            a[mf] = *(const bf16x8*)((const char*)sX + swzX(am + mf * 16, kb * 2 + s * 64 + kg));
#pragma unroll
        for (int nf = 0; nf < 4; ++nf)
            b[nf] = *(const bf16x8*)((const char*)sW + swzW(bo + nf * 16, s * 64 + kg));
#pragma unroll
        for (int mf = 0; mf < 4; ++mf)
#pragma unroll
            for (int nf = 0; nf < 4; ++nf)
                acc[mf][nf] = __builtin_amdgcn_mfma_f32_16x16x32_bf16(a[mf], b[nf], acc[mf][nf], 0, 0, 0);
    }
}

// ---------------------------------------------------------------------------
// QKV fused: stage x-tile once, run 6 GEMM-tiles (Wq,Wk,Wv x 2 o-halves).
// W staging pipelined: chunk k+1's global loads overlap chunk k's MFMAs.
// Wq/Wk epilogue: per-o sum & max over l -> atomics. Wv: bias + bf16 store.
// ---------------------------------------------------------------------------
__global__ __launch_bounds__(256, 2)
void qkv_kernel(const float* __restrict__ x, const ushortT* __restrict__ Wbf,
                const float* __restrict__ bv,
                float* __restrict__ qsum, unsigned* __restrict__ qmax,
                float* __restrict__ ksum, unsigned* __restrict__ kmax,
                ushortT* __restrict__ vbuf)
{
    __shared__ ushortT sX[128 * 256];   // 64 KiB
    __shared__ ushortT sW[128 * 64];    // 16 KiB
    const int tid = threadIdx.x;
    const int lane = tid & 63;
    const int wv = tid >> 6;
    const int wr = wv >> 1, wc = wv & 1;
    const int lbase = blockIdx.x * 128;
    const int z = blockIdx.y;
    const int n = z >> 4;

    stage_x<false>(x, sX, z, lbase, tid);

    ushort8_t wreg[4];
    stage_w_load(Wbf + (size_t)n * CHN * CHN, 0, 0, tid, wreg);   // w=0, ot=0, kb=0

    for (int w = 0; w < 3; ++w) {
        for (int ot = 0; ot < 2; ++ot) {
            const int obase = ot * 128;
            f32x4 acc[4][4];
            const f32x4 z4 = {0.f, 0.f, 0.f, 0.f};
#pragma unroll
            for (int mf = 0; mf < 4; ++mf)
#pragma unroll
                for (int nf = 0; nf < 4; ++nf) acc[mf][nf] = z4;

#pragma unroll
            for (int kb = 0; kb < 4; ++kb) {
                __syncthreads();                       // prev MFMA done reading sW
                stage_w_write(sW, tid, wreg);
                int cidx = (w * 2 + ot) * 4 + kb + 1;  // next chunk 1..24
                if (cidx < 24) {
                    int nw = cidx >> 3, not_ = (cidx >> 2) & 1, nkb = cidx & 3;
                    stage_w_load(Wbf + ((size_t)nw * NBR + n) * CHN * CHN,
                                 not_ * 128, nkb * 64, tid, wreg);
                }
                __syncthreads();                       // sW ready
                mfma_chunk(sX, sW, acc, wr, wc, lane, kb * 64);
            }

            if (w < 2) {
                float* rs = (w == 0) ? qsum : ksum;
                unsigned* rm = (w == 0) ? qmax : kmax;
#pragma unroll
                for (int nf = 0; nf < 4; ++nf) {
                    float s = 0.f, m = -3.4e38f;
#pragma unroll
                    for (int mf = 0; mf < 4; ++mf)
#pragma unroll
                        for (int r = 0; r < 4; ++r) {
                            float v = acc[mf][nf][r];
                            s += v; m = fmaxf(m, v);
                        }
                    s += __shfl_xor(s, 16); s += __shfl_xor(s, 32);
                    m = fmaxf(m, __shfl_xor(m, 16)); m = fmaxf(m, __shfl_xor(m, 32));
                    if (lane < 16) {
                        int o = obase + wc * 64 + nf * 16 + lane;
                        atomicAdd(&rs[z * CHN + o], s);
                        atomicMax(&rm[z * CHN + o], encf(m));
                    }
                }
            } else {
#pragma unroll
                for (int nf = 0; nf < 4; ++nf) {
                    int o = obase + wc * 64 + nf * 16 + (lane & 15);
                    float bvv = bv[n * CHN + o];
#pragma unroll
                    for (int mf = 0; mf < 4; ++mf) {
                        int l = lbase + wr * 64 + mf * 16 + ((lane >> 4) << 2);
                        ushort4_t u;
#pragma unroll
                        for (int r = 0; r < 4; ++r) u[r] = f2bf(acc[mf][nf][r] + bvv);
                        *(ushort4_t*)(vbuf + (size_t)(z * CHN + o) * LEN + l) = u;
                    }
                }
            }
        }
    }
}

// ---------------------------------------------------------------------------
// O GEMM: agg (bf16) -> out_pre (bf16) + BN partial stats. Same W pipeline.
// ---------------------------------------------------------------------------
__global__ __launch_bounds__(256, 2)
void ogemm_kernel(const ushortT* __restrict__ agg, const ushortT* __restrict__ Wbo,
                  const float* __restrict__ bo_,
                  float* __restrict__ bnsum, float* __restrict__ bnss,
                  ushortT* __restrict__ outpre)
{
    __shared__ ushortT sX[128 * 256];
    __shared__ ushortT sW[128 * 64];
    const int tid = threadIdx.x;
    const int lane = tid & 63;
    const int wv = tid >> 6;
    const int wr = wv >> 1, wc = wv & 1;
    const int lbase = blockIdx.x * 128;
    const int z = blockIdx.y;
    const int n = z >> 4;
    const ushortT* Wb = Wbo + (size_t)n * CHN * CHN;   // per-branch slice

    stage_x<true>(agg, sX, z, lbase, tid);

    ushort8_t wreg[4];
    stage_w_load(Wb, 0, 0, tid, wreg);

    for (int ot = 0; ot < 2; ++ot) {
        const int obase = ot * 128;
        f32x4 acc[4][4];
        const f32x4 z4 = {0.f, 0.f, 0.f, 0.f};
#pragma unroll
        for (int mf = 0; mf < 4; ++mf)
#pragma unroll
            for (int nf = 0; nf < 4; ++nf) acc[mf][nf] = z4;

#pragma unroll
        for (int kb = 0; kb < 4; ++kb) {
            __syncthreads();
            stage_w_write(sW, tid, wreg);
            int cidx = ot * 4 + kb + 1;   // next chunk 1..8
            if (cidx < 8) {
                int not_ = (cidx >> 2) & 1, nkb = cidx & 3;
                stage_w_load(Wb, not_ * 128, nkb * 64, tid, wreg);
            }
            __syncthreads();
            mfma_chunk(sX, sW, acc, wr, wc, lane, kb * 64);
        }

#pragma unroll
        for (int nf = 0; nf < 4; ++nf) {
            int o = obase + wc * 64 + nf * 16 + (lane & 15);
            float bb = bo_[n * CHN + o];
            float s = 0.f, q2 = 0.f;
#pragma unroll
            for (int mf = 0; mf < 4; ++mf) {
                int l = lbase + wr * 64 + mf * 16 + ((lane >> 4) << 2);
                ushort4_t u;
#pragma unroll
                for (int r = 0; r < 4; ++r) {
                    float v = acc[mf][nf][r] + bb;
                    u[r] = f2bf(v);
                    s += v; q2 += v * v;
                }
                *(ushort4_t*)(outpre + (size_t)(z * CHN + o) * LEN + l) = u;
            }
            s += __shfl_xor(s, 16); s += __shfl_xor(s, 32);
            q2 += __shfl_xor(q2, 16); q2 += __shfl_xor(q2, 32);
            if (lane < 16) {
                atomicAdd(&bnsum[n * CHN + o], s);
                atomicAdd(&bnss[n * CHN + o], q2);
            }
        }
    }
}

// convert all 4 weight tensors fp32 -> bf16 into Wbf [w][n][o][c]
__global__ void wcvt_kernel(const float* __restrict__ Wq, const float* __restrict__ Wk,
                            const float* __restrict__ Wv, const float* __restrict__ Wo,
                            ushortT* __restrict__ Wbf)
{
    int t = blockIdx.x * 256 + threadIdx.x;    // float4 units
    const int per = W_EL / 4;                  // 65536
    if (t < 4 * per) {
        const float* srcs[4] = {Wq, Wk, Wv, Wo};
        int w = t / per;
        int r = t - w * per;
        float4 f = *(const float4*)(srcs[w] + (size_t)r * 4);
        ushort4_t u = {f2bf(f.x), f2bf(f.y), f2bf(f.z), f2bf(f.w)};
        *(ushort4_t*)(Wbf + (size_t)w * W_EL + (size_t)r * 4) = u;
    }
}

// ---------------------------------------------------------------------------
// attention coefficients: scores[i,j,b] = (sum_c sq*sk) * edge_w[i,j] / 64
// attn[i,j,b] = softmax_j(scores) * softmax(branch_imp)[j]
// sq = qsum/L + dec(qmax) + 2*bq  (mean+max, bias shifts both by bq)
// ---------------------------------------------------------------------------
__global__ void attn_kernel(const float* __restrict__ qsum, const unsigned* __restrict__ qmax,
                            const float* __restrict__ ksum, const unsigned* __restrict__ kmax,
                            const float* __restrict__ bq, const float* __restrict__ bk,
                            const float* __restrict__ edge, const float* __restrict__ bimp,
                            float* __restrict__ attn)
{
    __shared__ float sc[NBR][NBR][BSZ];
    int tid = threadIdx.x;           // 256 threads == 4*4*16
    int i = tid >> 6, j = (tid >> 4) & 3, b = tid & 15;
    float s = 0.f;
    const float invL = 1.0f / (float)LEN;
    for (int c = 0; c < CHN; ++c) {
        int qi = (i * BSZ + b) * CHN + c;
        int ki = (j * BSZ + b) * CHN + c;
        float sq = qsum[qi] * invL + decf(qmax[qi]) + 2.f * bq[i * CHN + c];
        float sk = ksum[ki] * invL + decf(kmax[ki]) + 2.f * bk[j * CHN + c];
        s += sq * sk;
    }
    sc[i][j][b] = s * edge[i * 4 + j] * (1.0f / 64.0f);
    __syncthreads();
    if (tid < 64) {
        int ii = tid >> 4, bb = tid & 15;
        float m = -3.4e38f;
        for (int jj = 0; jj < 4; ++jj) m = fmaxf(m, sc[ii][jj][bb]);
        float e[4]; float sum = 0.f;
        for (int jj = 0; jj < 4; ++jj) { e[jj] = __expf(sc[ii][jj][bb] - m); sum += e[jj]; }
        float bm = fmaxf(fmaxf(bimp[0], bimp[1]), fmaxf(bimp[2], bimp[3]));
        float be[4]; float bs = 0.f;
        for (int jj = 0; jj < 4; ++jj) { be[jj] = __expf(bimp[jj] - bm); bs += be[jj]; }
        for (int jj = 0; jj < 4; ++jj)
            attn[(ii * 4 + jj) * BSZ + bb] = (e[jj] / sum) * (be[jj] / bs);
    }
}

// agg[i,b,c,l] = sum_j attn[i,j,b] * v[j,b,c,l]   (bf16 in, bf16 out)
__global__ __launch_bounds__(256)
void agg_kernel(const ushortT* __restrict__ v, const float* __restrict__ attn,
                ushortT* __restrict__ agg)
{
    __shared__ float sa[256];
    sa[threadIdx.x] = attn[threadIdx.x];
    __syncthreads();
    const long long U = (long long)BSZ * CHN * (LEN / 8);   // 2,097,152 units of 8
    for (long long u = (long long)blockIdx.x * blockDim.x + threadIdx.x; u < U;
         u += (long long)gridDim.x * blockDim.x) {
        int l0 = (int)(u & 511) * 8;
        int c  = (int)(u >> 9) & 255;
        int b  = (int)(u >> 17);
        float vv[4][8];
#pragma unroll
        for (int j = 0; j < 4; ++j) {
            ushort8_t raw = *(const ushort8_t*)(v + (((size_t)(j * BSZ + b) * CHN + c) * LEN) + l0);
#pragma unroll
            for (int e = 0; e < 8; ++e) vv[j][e] = bf2f(raw[e]);
        }
#pragma unroll
        for (int i = 0; i < 4; ++i) {
            float a0 = sa[(i * 4 + 0) * BSZ + b];
            float a1 = sa[(i * 4 + 1) * BSZ + b];
            float a2 = sa[(i * 4 + 2) * BSZ + b];
            float a3 = sa[(i * 4 + 3) * BSZ + b];
            ushort8_t out;
#pragma unroll
            for (int e = 0; e < 8; ++e) {
                float r = a0 * vv[0][e] + a1 * vv[1][e] + a2 * vv[2][e] + a3 * vv[3][e];
                out[e] = f2bf(r);
            }
            *(ushort8_t*)(agg + (((size_t)(i * BSZ + b) * CHN + c) * LEN) + l0) = out;
        }
    }
}

// finalize BN affine: scale = gamma*rsqrt(var+eps), shift = beta - mean*scale
__global__ void bnfin_kernel(const float* __restrict__ bnsum, const float* __restrict__ bnss,
                             const float* __restrict__ gamma, const float* __restrict__ beta,
                             float* __restrict__ scl, float* __restrict__ shf)
{
    int t = blockIdx.x * blockDim.x + threadIdx.x;   // 0..1023 = n*256+c
    if (t < NBR * CHN) {
        const float inv = 1.0f / (float)BL;
        float mean = bnsum[t] * inv;
        float var = bnss[t] * inv - mean * mean;
        float rs = rsqrtf(var + BN_EPS);
        float s = gamma[t] * rs;
        scl[t] = s;
        shf[t] = beta[t] - mean * s;
    }
}

// out = relu(out_pre*scale + shift) + x
__global__ __launch_bounds__(256)
void final_kernel(const ushortT* __restrict__ outpre, const float* __restrict__ x,
                  const float* __restrict__ scl, const float* __restrict__ shf,
                  float* __restrict__ out)
{
    const long long U = (long long)NB_B * CHN * (LEN / 8);   // 8,388,608 units of 8
    for (long long u = (long long)blockIdx.x * blockDim.x + threadIdx.x; u < U;
         u += (long long)gridDim.x * blockDim.x) {
        int l0 = (int)(u & 511) * 8;
        int c  = (int)(u >> 9) & 255;
        int zz = (int)(u >> 17);          // n*16+b
        int n  = zz >> 4;
        size_t base = ((size_t)zz * CHN + c) * LEN + l0;
        ushort8_t op = *(const ushort8_t*)(outpre + base);
        float4 x0 = *(const float4*)(x + base);
        float4 x1 = *(const float4*)(x + base + 4);
        float sc = scl[n * CHN + c];
        float sh = shf[n * CHN + c];
        float xr[8] = {x0.x, x0.y, x0.z, x0.w, x1.x, x1.y, x1.z, x1.w};
        float res[8];
#pragma unroll
        for (int e = 0; e < 8; ++e) {
            float bn = bf2f(op[e]) * sc + sh;
            res[e] = fmaxf(bn, 0.f) + xr[e];
        }
        float4 o0 = {res[0], res[1], res[2], res[3]};
        float4 o1 = {res[4], res[5], res[6], res[7]};
        *(float4*)(out + base) = o0;
        *(float4*)(out + base + 4) = o1;
    }
}

extern "C" void kernel_launch(void* const* d_in, const int* in_sizes, int n_in,
                              void* d_out, int out_size, void* d_ws, size_t ws_size,
                              hipStream_t stream)
{
    const float* x     = (const float*)d_in[0];
    const float* Wq    = (const float*)d_in[1];
    const float* bq    = (const float*)d_in[2];
    const float* Wk    = (const float*)d_in[3];
    const float* bk    = (const float*)d_in[4];
    const float* Wv    = (const float*)d_in[5];
    const float* bv    = (const float*)d_in[6];
    const float* Wo    = (const float*)d_in[7];
    const float* bo    = (const float*)d_in[8];
    const float* gamma = (const float*)d_in[9];
    const float* beta  = (const float*)d_in[10];
    const float* edge  = (const float*)d_in[11];
    const float* bimp  = (const float*)d_in[12];

    char* ws = (char*)d_ws;
    const size_t V_BYTES = (size_t)NBR * BSZ * CHN * LEN * 2;   // 128 MiB (bf16)
    ushortT* vbuf = (ushortT*)ws;            // v, later reused for out_pre
    size_t off = V_BYTES;
    float*    qsum = (float*)(ws + off);    off += 65536;
    unsigned* qmax = (unsigned*)(ws + off); off += 65536;
    float*    ksum = (float*)(ws + off);    off += 65536;
    unsigned* kmax = (unsigned*)(ws + off); off += 65536;
    float*    attn = (float*)(ws + off);    off += 1024;
    float*    bnsum= (float*)(ws + off);    off += 4096;
    float*    bnss = (float*)(ws + off);    off += 4096;
    float*    scl  = (float*)(ws + off);    off += 4096;
    float*    shf  = (float*)(ws + off);    off += 4096;

    // zero the small accumulators (sum=0; max uses encoding where 0 < enc(-inf))
    hipMemsetAsync(ws + V_BYTES, 0, off - V_BYTES, stream);

    ushortT* aggbuf = (ushortT*)d_out;   // agg staged as bf16 in d_out (first 128 MiB)
    float*   outf   = (float*)d_out;
    // bf16 weights live in the (unused until final) second half of d_out
    ushortT* Wbf = (ushortT*)((char*)d_out + ((size_t)134217728));

    wcvt_kernel<<<(4 * W_EL / 4 + 255) / 256, 256, 0, stream>>>(Wq, Wk, Wv, Wo, Wbf);

    dim3 gq(LEN / 128, NB_B);   // (32, 64)
    qkv_kernel<<<gq, 256, 0, stream>>>(x, Wbf, bv, qsum, qmax, ksum, kmax, vbuf);
    attn_kernel<<<1, 256, 0, stream>>>(qsum, qmax, ksum, kmax, bq, bk, edge, bimp, attn);
    agg_kernel<<<2048, 256, 0, stream>>>(vbuf, attn, aggbuf);
    ogemm_kernel<<<gq, 256, 0, stream>>>(aggbuf, Wbf + (size_t)3 * W_EL, bo, bnsum, bnss, vbuf);
    bnfin_kernel<<<4, 256, 0, stream>>>(bnsum, bnss, gamma, beta, scl, shf);
    final_kernel<<<8192, 256, 0, stream>>>(vbuf, x, scl, shf, outf);
}